// Round 4
// baseline (286.117 us; speedup 1.0000x reference)
//
#include <hip/hip_runtime.h>
#include <math.h>

#define CDIM 256
#define CKD  32
#define NPIX 4096
#define BATCH 4
#define NMACRO (NPIX / 64)

typedef __attribute__((ext_vector_type(8)))  short bf16x8;
typedef __attribute__((ext_vector_type(16))) float f32x16;

__device__ inline ushort f2bf(float x) {
    unsigned u = __float_as_uint(x);
    u += 0x7fffu + ((u >> 16) & 1u);   // round-to-nearest-even
    return (ushort)(u >> 16);
}

#define LDS_ASYNC16(gptr, lptr) \
  __builtin_amdgcn_global_load_lds((const __attribute__((address_space(1))) void*)(gptr), \
                                   (__attribute__((address_space(3))) void*)(lptr), 16, 0, 0)

// ---------------- Kernel 1: projections -> bf16 f, g, hh^T ----------------
// Block = 256 thr, 32 pixels. hh register-blocked 4px x 8ch per thread.
// hh^T stored via LDS transpose -> 16-B stores. f/g: 8px x 1 out per thread.
__global__ __launch_bounds__(256) void proj_kernel(
    const float* __restrict__ x,   // [B*N, 256]
    const float* __restrict__ Wf,  // [256, 32]
    const float* __restrict__ bfp, // [32]
    const float* __restrict__ Wg,  // [256, 32]
    const float* __restrict__ bgp, // [32]
    const float* __restrict__ Wh,  // [256, 256]
    const float* __restrict__ bhp, // [256]
    ushort* __restrict__ fo,       // bf16 [B*N, 32]   (keys)
    ushort* __restrict__ go,       // bf16 [B*N, 32]   (queries)
    ushort* __restrict__ ht)       // bf16 [B, 256, N] (values, transposed)
{
    __shared__ float  xs[32][256];   // 32 KB
    __shared__ ushort tr[256 * 32];  // 16 KB transpose buffer (octet-swizzled)

    const int tid = threadIdx.x;
    const long long pix0 = (long long)blockIdx.x * 32;
    const int b  = (int)(pix0 >> 12);
    const int n0 = (int)(pix0 & (NPIX - 1));

    const float4* xg = (const float4*)(x + pix0 * CDIM);
    #pragma unroll
    for (int i = 0; i < 8; ++i) {
        int fi = i * 256 + tid;
        float4 v = xg[fi];
        *(float4*)&xs[fi >> 6][(fi & 63) << 2] = v;
    }
    __syncthreads();

    // ---- hh: thread = pixels pg*4..+3, channels {ci*4..+3, 128+ci*4..+3}
    {
        const int pg = tid >> 5;    // 0..7
        const int ci = tid & 31;
        float acc[4][8];
        #pragma unroll
        for (int i = 0; i < 4; ++i)
            #pragma unroll
            for (int j = 0; j < 8; ++j) acc[i][j] = 0.f;

        #pragma unroll 4
        for (int k = 0; k < CDIM; ++k) {
            float4 w0 = *(const float4*)&Wh[k * CDIM + ci * 4];
            float4 w1 = *(const float4*)&Wh[k * CDIM + 128 + ci * 4];
            #pragma unroll
            for (int i = 0; i < 4; ++i) {
                float xv = xs[pg * 4 + i][k];   // broadcast within half-wave
                acc[i][0] += xv * w0.x; acc[i][1] += xv * w0.y;
                acc[i][2] += xv * w0.z; acc[i][3] += xv * w0.w;
                acc[i][4] += xv * w1.x; acc[i][5] += xv * w1.y;
                acc[i][6] += xv * w1.z; acc[i][7] += xv * w1.w;
            }
        }
        // bias + write to transpose buffer (swizzled px-octets)
        #pragma unroll
        for (int j = 0; j < 8; ++j) {
            int c = (j < 4) ? (ci * 4 + j) : (128 + ci * 4 + (j - 4));
            float bias = bhp[c];
            int s = (c >> 2) & 3;
            #pragma unroll
            for (int i = 0; i < 4; ++i) {
                int px = pg * 4 + i;
                int jp = ((px >> 3) + s) & 3;
                tr[c * 32 + jp * 8 + (px & 7)] = f2bf(acc[i][j] + bias);
            }
        }
    }
    __syncthreads();
    // ---- readback: thread = channel, 4 x 16-B stores to ht^T
    {
        const int c = tid;
        const int s = (c >> 2) & 3;
        ushort* dst = ht + ((long long)(b * CDIM + c)) * NPIX + n0;
        #pragma unroll
        for (int po = 0; po < 4; ++po) {
            bf16x8 v = *(const bf16x8*)&tr[c * 32 + (((po + s) & 3) * 8)];
            *(bf16x8*)(dst + po * 8) = v;
        }
    }

    // ---- f/g: thread = 8 pixels x 1 output column
    {
        const int oc = tid & 63;
        const int pb = (tid >> 6) * 8;
        const bool isf = (oc < CKD);
        const int col = oc & (CKD - 1);
        const float* W = isf ? Wf : Wg;
        float a[8];
        #pragma unroll
        for (int i = 0; i < 8; ++i) a[i] = 0.f;
        #pragma unroll 4
        for (int k = 0; k < CDIM; ++k) {
            float wv = W[k * CKD + col];
            #pragma unroll
            for (int i = 0; i < 8; ++i) a[i] += xs[pb + i][k] * wv;
        }
        float bb = isf ? bfp[col] : bgp[col];
        ushort* dst = isf ? fo : go;
        #pragma unroll
        for (int i = 0; i < 8; ++i)
            dst[(pix0 + pb + i) * CKD + col] = f2bf(a[i] + bb);
    }
}

// ---------------- Kernel 2: MFMA attention, chunk-transposed LDS ---------
// 256 blocks (1/CU), 4 waves. Block = 64 q x 256 ch, 64-key macros.
// Wave w: QK S-tile (qh=w&1, kh=w>>1); PV 64q x 64ch (2x2 register tiles).
// Chunk = 16 B = 8 consecutive keys (hh, p) or 8 ck (f).
//   hh: chunk (c, j)   at slot j*256 + c              (j = key-octet 0..7)
//   f : chunk (key, j) at slot j*64 + key             (j = ck-octet 0..3)
//   p : chunk (q, j)   at slot j*64 + ((q + j) & 63)  (rotation: write-bank spread)
__global__ __launch_bounds__(256) void attn_kernel(
    const float*  __restrict__ x,
    const ushort* __restrict__ fk,   // bf16 [B*N,32] keys
    const ushort* __restrict__ gq,   // bf16 [B*N,32] queries
    const ushort* __restrict__ hv,   // bf16 [B,256,N] values^T
    float* __restrict__ out)
{
    __shared__ ushort hh_lds[8 * 256 * 8];   // 32 KB, single buffer
    __shared__ ushort f_lds[2][4 * 64 * 8];  // 8 KB total, double buffer
    __shared__ ushort p_lds[8 * 64 * 8];     // 8 KB
    __shared__ float  l_red[2][64];

    const int tid  = threadIdx.x;
    const int w    = tid >> 6;
    const int lane = tid & 63;
    const int hl   = lane >> 5;   // K-half selector for MFMA fragments
    const int ln   = lane & 31;

    // XCD-aware decode: each XCD pair-serves one batch
    const int bid = blockIdx.x;
    const int b   = (bid & 7) >> 1;
    const int qb  = ((bid >> 3) << 1) | (bid & 1);

    const int qh = w & 1;     // wave's QK q-tile
    const int kh = w >> 1;    // wave's QK key-tile
    const int cb = w * 64;    // wave's PV channel base

    const long long bbase = (long long)b * NPIX;
    const int q0 = qb * 64;

    // g A-frags (wave's 32 q rows), live in registers all kernel
    const ushort* gp = gq + (bbase + q0 + qh * 32 + ln) * CKD;
    const bf16x8 ga0 = *(const bf16x8*)(gp + hl * 8);
    const bf16x8 ga1 = *(const bf16x8*)(gp + 16 + hl * 8);

    const ushort* hbase = hv + (long long)b * CDIM * NPIX;
    const ushort* fbase = fk + bbase * CKD;

    // ---- pre-stage f for macro 0: thread -> (key=tid&63, ck-octet j=tid>>6)
    {
        int key = tid & 63, j = tid >> 6;
        LDS_ASYNC16(fbase + (long long)key * CKD + j * 8, &f_lds[0][tid * 8]);
    }

    f32x16 acc00 = {0,0,0,0,0,0,0,0,0,0,0,0,0,0,0,0};
    f32x16 acc01 = {0,0,0,0,0,0,0,0,0,0,0,0,0,0,0,0};
    f32x16 acc10 = {0,0,0,0,0,0,0,0,0,0,0,0,0,0,0,0};
    f32x16 acc11 = {0,0,0,0,0,0,0,0,0,0,0,0,0,0,0,0};
    float lsum[16];
    #pragma unroll
    for (int r = 0; r < 16; ++r) lsum[r] = 0.f;

    for (int kt = 0; kt < NMACRO; ++kt) {
        const int cur = kt & 1;
        const int k0 = kt * 64;
        __syncthreads();   // TOP: prev PV's hh/p LDS reads retired in all waves

        // ---- hh staging for THIS macro: thread = channel tid, 8 key-octets
        //      dest slot i*256 + tid == chunk (c=tid, j=i); lane-contiguous
        #pragma unroll
        for (int i = 0; i < 8; ++i)
            LDS_ASYNC16(hbase + (long long)tid * NPIX + k0 + i * 8,
                        &hh_lds[(i * 256 + tid) * 8]);
        // ---- f staging for NEXT macro
        if (kt + 1 < NMACRO) {
            int key = tid & 63, j = tid >> 6;
            LDS_ASYNC16(fbase + (long long)(k0 + 64 + key) * CKD + j * 8,
                        &f_lds[cur ^ 1][tid * 8]);
        }

        // ---- QK: S[32q x 32k] for wave's (qh, kh)
        const int keyq = kh * 32 + ln;
        bf16x8 fb0 = *(const bf16x8*)&f_lds[cur][(hl * 64 + keyq) * 8];
        bf16x8 fb1 = *(const bf16x8*)&f_lds[cur][((2 + hl) * 64 + keyq) * 8];
        f32x16 S = {0,0,0,0,0,0,0,0,0,0,0,0,0,0,0,0};
        S = __builtin_amdgcn_mfma_f32_32x32x16_bf16(ga0, fb0, S, 0, 0, 0);
        S = __builtin_amdgcn_mfma_f32_32x32x16_bf16(ga1, fb1, S, 0, 0, 0);

        // ---- p = exp(min(s,80)): no-max softmax (|s|<~40, R2-proven);
        //      clamp = NaN insurance. Write P chunk (q=qrow, j=jw), elem pi.
        {
            const int jw = kh * 4 + (ln >> 3);
            const int pi = ln & 7;
            #pragma unroll
            for (int r = 0; r < 16; ++r) {
                float p = __expf(fminf(S[r], 80.f));
                lsum[r] += p;
                int qrow = qh * 32 + (r & 3) + 8 * (r >> 2) + 4 * hl;
                p_lds[(jw * 64 + ((qrow + jw) & 63)) * 8 + pi] = f2bf(p);
            }
        }
        __syncthreads();   // MID: drains vmcnt (hh+f staged); P visible

        // ---- PV: O[64q x 64ch] over K=64, 2x2 register tiles
        #pragma unroll
        for (int kk = 0; kk < 4; ++kk) {
            const int j = kk * 2 + hl;
            bf16x8 pa0 = *(const bf16x8*)&p_lds[(j * 64 + ((ln + j) & 63)) * 8];
            bf16x8 pa1 = *(const bf16x8*)&p_lds[(j * 64 + ((32 + ln + j) & 63)) * 8];
            bf16x8 hb0 = *(const bf16x8*)&hh_lds[(j * 256 + cb + ln) * 8];
            bf16x8 hb1 = *(const bf16x8*)&hh_lds[(j * 256 + cb + 32 + ln) * 8];
            acc00 = __builtin_amdgcn_mfma_f32_32x32x16_bf16(pa0, hb0, acc00, 0, 0, 0);
            acc01 = __builtin_amdgcn_mfma_f32_32x32x16_bf16(pa0, hb1, acc01, 0, 0, 0);
            acc10 = __builtin_amdgcn_mfma_f32_32x32x16_bf16(pa1, hb0, acc10, 0, 0, 0);
            acc11 = __builtin_amdgcn_mfma_f32_32x32x16_bf16(pa1, hb1, acc11, 0, 0, 0);
        }
    }

    // ---- l: reduce over 32 key-cols per wave, combine kh halves via LDS
    #pragma unroll
    for (int m = 1; m <= 16; m <<= 1)
        #pragma unroll
        for (int r = 0; r < 16; ++r)
            lsum[r] += __shfl_xor(lsum[r], m, 64);
    if (ln == 0) {
        #pragma unroll
        for (int r = 0; r < 16; ++r) {
            int qrow = qh * 32 + (r & 3) + 8 * (r >> 2) + 4 * hl;
            l_red[kh][qrow] = lsum[r];
        }
    }
    __syncthreads();

    // ---- epilogue: out = x + o/l (coalesced 32-float runs)
    #pragma unroll
    for (int r = 0; r < 16; ++r) {
        const int row = (r & 3) + 8 * (r >> 2) + 4 * hl;
        {   // q-tile 0
            int q_loc = row;
            float linv = 1.f / (l_red[0][q_loc] + l_red[1][q_loc]);
            long long rg = (bbase + q0 + q_loc) * CDIM + cb + ln;
            out[rg]      = x[rg]      + acc00[r] * linv;
            out[rg + 32] = x[rg + 32] + acc01[r] * linv;
        }
        {   // q-tile 1
            int q_loc = 32 + row;
            float linv = 1.f / (l_red[0][q_loc] + l_red[1][q_loc]);
            long long rg = (bbase + q0 + q_loc) * CDIM + cb + ln;
            out[rg]      = x[rg]      + acc10[r] * linv;
            out[rg + 32] = x[rg + 32] + acc11[r] * linv;
        }
    }
}

extern "C" void kernel_launch(void* const* d_in, const int* in_sizes, int n_in,
                              void* d_out, int out_size, void* d_ws, size_t ws_size,
                              hipStream_t stream) {
    const float* x  = (const float*)d_in[0];
    const float* Wf = (const float*)d_in[1];
    const float* bf = (const float*)d_in[2];
    const float* Wg = (const float*)d_in[3];
    const float* bg = (const float*)d_in[4];
    const float* Wh = (const float*)d_in[5];
    const float* bh = (const float*)d_in[6];
    float* out = (float*)d_out;

    ushort* fbf = (ushort*)d_ws;            // bf16 keys    [B*N,32]
    ushort* gbf = fbf + BATCH * NPIX * CKD; // bf16 queries [B*N,32]
    ushort* ht  = gbf + BATCH * NPIX * CKD; // bf16 values^T [B,256,N] (~10 MB)

    proj_kernel<<<dim3(BATCH * NPIX / 32), 256, 0, stream>>>(
        x, Wf, bf, Wg, bg, Wh, bh, fbf, gbf, ht);
    attn_kernel<<<dim3(256), 256, 0, stream>>>(
        x, fbf, gbf, ht, out);
}

// Round 6
// 212.837 us; speedup vs baseline: 1.3443x; 1.3443x over previous
//
#include <hip/hip_runtime.h>
#include <math.h>

#define CDIM 256
#define CKD  32
#define NPIX 4096
#define BATCH 4
#define NMACRO (NPIX / 64)

typedef __attribute__((ext_vector_type(8)))  short bf16x8;
typedef __attribute__((ext_vector_type(16))) float f32x16;

__device__ inline ushort f2bf(float x) {
    unsigned u = __float_as_uint(x);
    u += 0x7fffu + ((u >> 16) & 1u);   // round-to-nearest-even
    return (ushort)(u >> 16);
}

#define LDS_ASYNC16(gptr, lptr) \
  __builtin_amdgcn_global_load_lds((const __attribute__((address_space(1))) void*)(gptr), \
                                   (__attribute__((address_space(3))) void*)(lptr), 16, 0, 0)

// ---------------- Kernel 0: prep Wt[320][256] bf16 = [Wh^T; Wf^T; Wg^T] ----
__global__ __launch_bounds__(256) void prep_kernel(
    const float* __restrict__ Wh, const float* __restrict__ Wf,
    const float* __restrict__ Wg, ushort* __restrict__ Wt)
{
    const int k = blockIdx.x;     // 0..255 (input channel)
    const int c = threadIdx.x;    // 0..255 (output channel)
    Wt[c * 256 + k] = f2bf(Wh[k * 256 + c]);            // coalesced read
    if (c < 32)
        Wt[(256 + c) * 256 + k] = f2bf(Wf[k * CKD + c]);
    else if (c < 64)
        Wt[(288 + (c - 32)) * 256 + k] = f2bf(Wg[k * CKD + (c - 32)]);
}

// ---------------- Kernel 1: MFMA projections ------------------------------
// 256 blocks (1/CU), 4 waves, 64 px each. K=256 in 8 slabs of 32, dbuf LDS.
// Orientation 1 (hh): D = Wt_h(A, rows=c) x X^T(B, cols=px) -> D(c,px) goes
//   straight to tiled ht[b][kt][c][key]. Orientation 2 (f/g): D = X(A) x
//   Wt_fg(B) -> row-major f/g. X frags shared between both orientations.
// LDS rows are 4 chunks of 16B; chunk o stored at slot (o + row/2) & 3.
// g additionally stored as hi/lo bf16 pair (lo = residual) for accurate QK.
__global__ __launch_bounds__(256) void proj_kernel(
    const float*  __restrict__ x,    // [B*N, 256] fp32
    const ushort* __restrict__ Wt,   // [320, 256] bf16
    const float*  __restrict__ bfp, const float* __restrict__ bgp,
    const float*  __restrict__ bhp,
    ushort* __restrict__ fo,         // bf16 [B*N, 32]
    ushort* __restrict__ go,         // bf16 [B*N, 32]
    ushort* __restrict__ glo,        // bf16 [B*N, 32]  g residual
    ushort* __restrict__ ht)         // bf16 [B*64][256][64] tiled values^T
{
    __shared__ ushort xls[2][64 * 32];    //  8 KB
    __shared__ ushort wls[2][320 * 32];   // 40 KB

    const int tid  = threadIdx.x;
    const int w    = tid >> 6;
    const int lane = tid & 63;
    const int hl   = lane >> 5;
    const int ln   = lane & 31;
    const int bid  = blockIdx.x;
    const long long px0 = (long long)bid * 64;

    // X staging map (plain ds_write of cvt'd fp32)
    const int sx_px = tid >> 2, sx_o = tid & 3;
    const int sx_slot = (sx_o + (sx_px >> 1)) & 3;

    // ---- stage slab 0.  Wt staging: s = i*256+tid -> dest lane-linear
    //      (wave-uniform base + lane*16: REQUIRED by global_load_lds).
    #pragma unroll
    for (int i = 0; i < 5; ++i) {
        int s = i * 256 + tid;
        int n = s >> 2, o = ((s & 3) - (n >> 1)) & 3;
        LDS_ASYNC16(Wt + n * 256 + o * 8, &wls[0][s * 8]);
    }
    {
        const float* xp = x + (px0 + sx_px) * CDIM + sx_o * 8;
        float4 a = *(const float4*)xp, b2 = *(const float4*)(xp + 4);
        bf16x8 v;
        v[0]=f2bf(a.x); v[1]=f2bf(a.y); v[2]=f2bf(a.z); v[3]=f2bf(a.w);
        v[4]=f2bf(b2.x); v[5]=f2bf(b2.y); v[6]=f2bf(b2.z); v[7]=f2bf(b2.w);
        *(bf16x8*)&xls[0][sx_px * 32 + sx_slot * 8] = v;
    }

    f32x16 acc00={0,0,0,0,0,0,0,0,0,0,0,0,0,0,0,0};
    f32x16 acc01={0,0,0,0,0,0,0,0,0,0,0,0,0,0,0,0};
    f32x16 acc10={0,0,0,0,0,0,0,0,0,0,0,0,0,0,0,0};
    f32x16 acc11={0,0,0,0,0,0,0,0,0,0,0,0,0,0,0,0};
    f32x16 accfg={0,0,0,0,0,0,0,0,0,0,0,0,0,0,0,0};

    for (int sl = 0; sl < 8; ++sl) {
        const int cur = sl & 1;
        __syncthreads();                      // staging(sl) landed
        if (sl + 1 < 8) {
            const int nxt = cur ^ 1;
            #pragma unroll
            for (int i = 0; i < 5; ++i) {
                int s = i * 256 + tid;
                int n = s >> 2, o = ((s & 3) - (n >> 1)) & 3;
                LDS_ASYNC16(Wt + n * 256 + (sl + 1) * 32 + o * 8, &wls[nxt][s * 8]);
            }
            const float* xp = x + (px0 + sx_px) * CDIM + (sl + 1) * 32 + sx_o * 8;
            float4 a = *(const float4*)xp, b2 = *(const float4*)(xp + 4);
            bf16x8 v;
            v[0]=f2bf(a.x); v[1]=f2bf(a.y); v[2]=f2bf(a.z); v[3]=f2bf(a.w);
            v[4]=f2bf(b2.x); v[5]=f2bf(b2.y); v[6]=f2bf(b2.z); v[7]=f2bf(b2.w);
            *(bf16x8*)&xls[nxt][sx_px * 32 + sx_slot * 8] = v;
        }

        #pragma unroll
        for (int st = 0; st < 2; ++st) {
            const int o = st * 2 + hl;
            #define LDX(row) (*(const bf16x8*)&xls[cur][(row) * 32 + (((o) + ((row) >> 1)) & 3) * 8])
            #define LDW(n)   (*(const bf16x8*)&wls[cur][(n) * 32 + (((o) + ((n) >> 1)) & 3) * 8])
            bf16x8 xb0 = LDX(ln);
            bf16x8 xb1 = LDX(32 + ln);
            bf16x8 wa0 = LDW(w * 64 + ln);
            bf16x8 wa1 = LDW(w * 64 + 32 + ln);
            bf16x8 wfg = LDW(256 + (w >> 1) * 32 + ln);
            #undef LDX
            #undef LDW
            acc00 = __builtin_amdgcn_mfma_f32_32x32x16_bf16(wa0, xb0, acc00, 0, 0, 0);
            acc01 = __builtin_amdgcn_mfma_f32_32x32x16_bf16(wa0, xb1, acc01, 0, 0, 0);
            acc10 = __builtin_amdgcn_mfma_f32_32x32x16_bf16(wa1, xb0, acc10, 0, 0, 0);
            acc11 = __builtin_amdgcn_mfma_f32_32x32x16_bf16(wa1, xb1, acc11, 0, 0, 0);
            bf16x8 xa = (w & 1) ? xb1 : xb0;
            accfg = __builtin_amdgcn_mfma_f32_32x32x16_bf16(xa, wfg, accfg, 0, 0, 0);
        }
    }

    // ---- epilogue
    ushort* htt = ht + (long long)bid * (CDIM * 64);   // [c][key64] tile
    const bool isg = (w >> 1);
    const float bbfg = (isg ? bgp : bfp)[ln];
    ushort* fg_dst = isg ? go : fo;
    #pragma unroll
    for (int r = 0; r < 16; ++r) {
        const int rowD = (r & 3) + 8 * (r >> 2) + 4 * hl;
        {   // Wh tiles -> ht (D row = out channel, D col = pixel/key)
            int c0 = w * 64 + rowD, c1 = c0 + 32;
            float b0 = bhp[c0], b1 = bhp[c1];
            htt[c0 * 64 + ln]      = f2bf(acc00[r] + b0);
            htt[c0 * 64 + 32 + ln] = f2bf(acc01[r] + b0);
            htt[c1 * 64 + ln]      = f2bf(acc10[r] + b1);
            htt[c1 * 64 + 32 + ln] = f2bf(acc11[r] + b1);
        }
        {   // f/g (D row = pixel, D col = ck); g gets hi/lo split
            int pxr = (w & 1) * 32 + rowD;
            float v = accfg[r] + bbfg;
            ushort hi = f2bf(v);
            fg_dst[(px0 + pxr) * CKD + ln] = hi;
            if (isg) {
                float hif = __uint_as_float(((unsigned)hi) << 16);
                glo[(px0 + pxr) * CKD + ln] = f2bf(v - hif);
            }
        }
    }
}

// ---------------- Kernel 2: MFMA attention --------------------------------
// 256 blocks (1/CU), 4 waves. Block = 128 q x 128 ch (ch-split 2), 64-key
// macros, dbuf hh+f. Wave w: QK/exp for q-band w*32 (both key halves, l
// complete per wave); PV 2x2 tiles (q=(w&1)*64+{0,32}, c=(w>>1)*64+{0,32}).
// QK uses g = ga + gl (hi/lo bf16 pair) for ~fp32-accurate scores.
// Chunk layouts (16 B = 8 keys / 8 ck), rotation (j+row)&7 -> conflict-free:
//   hh: slot(c,j) = c*8 + ((j+c)&7)   p: slot(q,j) = q*8 + ((j+q)&7)
//   f : slot(key,j) = j*64 + key
__global__ __launch_bounds__(256) void attn_kernel(
    const float*  __restrict__ x,
    const ushort* __restrict__ fk,   // bf16 [B*N,32] keys
    const ushort* __restrict__ gq,   // bf16 [B*N,32] queries (hi)
    const ushort* __restrict__ glo,  // bf16 [B*N,32] queries (lo residual)
    const ushort* __restrict__ hv,   // bf16 tiled [B*64][256][64] values^T
    float* __restrict__ out)
{
    __shared__ ushort hh_lds[2][1024 * 8];  // 32 KB
    __shared__ ushort f_lds[2][256 * 8];    //  8 KB
    __shared__ ushort p_lds[1024 * 8];      // 16 KB
    __shared__ float  l_red[128];

    const int tid  = threadIdx.x;
    const int w    = tid >> 6;
    const int lane = tid & 63;
    const int hl   = lane >> 5;
    const int ln   = lane & 31;

    const int bid = blockIdx.x;
    const int chs = bid & 1;              // channel half
    const int b   = (bid >> 1) & 3;       // batch (XCD-paired via bid%8)
    const int qt  = bid >> 3;             // 0..31
    const int q0  = qt * 128;

    const long long bbase = (long long)b * NPIX;
    const ushort* fbase = fk + bbase * CKD;
    const ushort* htb   = hv + (long long)b * 64 * (CDIM * 64);  // batch tiles

    // g A-frags (hi+lo) for q-band w, in registers all kernel
    const ushort* gp  = gq  + (bbase + q0 + w * 32 + ln) * CKD;
    const ushort* glp = glo + (bbase + q0 + w * 32 + ln) * CKD;
    const bf16x8 ga0 = *(const bf16x8*)(gp + hl * 8);
    const bf16x8 ga1 = *(const bf16x8*)(gp + 16 + hl * 8);
    const bf16x8 gl0 = *(const bf16x8*)(glp + hl * 8);
    const bf16x8 gl1 = *(const bf16x8*)(glp + 16 + hl * 8);

    // ---- stage macro 0 (hh: 4 instr; f: 1 instr; dests lane-linear)
    #pragma unroll
    for (int i = 0; i < 4; ++i) {
        int s = i * 256 + tid;
        int c = s >> 3, j = ((s & 7) - c) & 7;
        LDS_ASYNC16(htb + (long long)(chs * 128 + c) * 64 + j * 8, &hh_lds[0][s * 8]);
    }
    LDS_ASYNC16(fbase + (long long)(tid & 63) * CKD + (tid >> 6) * 8, &f_lds[0][tid * 8]);

    f32x16 acc00={0,0,0,0,0,0,0,0,0,0,0,0,0,0,0,0};
    f32x16 acc01={0,0,0,0,0,0,0,0,0,0,0,0,0,0,0,0};
    f32x16 acc10={0,0,0,0,0,0,0,0,0,0,0,0,0,0,0,0};
    f32x16 acc11={0,0,0,0,0,0,0,0,0,0,0,0,0,0,0,0};
    float lsum[16];
    #pragma unroll
    for (int r = 0; r < 16; ++r) lsum[r] = 0.f;

    for (int kt = 0; kt < NMACRO; ++kt) {
        const int cur = kt & 1;
        __syncthreads();   // TOP: staging(kt) drained; prev PV p-reads retired

        // ---- QK: S for q-band w vs keys 0..31 (S0) and 32..63 (S1)
        f32x16 S0={0,0,0,0,0,0,0,0,0,0,0,0,0,0,0,0};
        f32x16 S1={0,0,0,0,0,0,0,0,0,0,0,0,0,0,0,0};
        {
            const int jf0 = hl, jf1 = 2 + hl;
            bf16x8 fb00 = *(const bf16x8*)&f_lds[cur][(jf0 * 64 + ln) * 8];
            bf16x8 fb01 = *(const bf16x8*)&f_lds[cur][(jf0 * 64 + 32 + ln) * 8];
            bf16x8 fb10 = *(const bf16x8*)&f_lds[cur][(jf1 * 64 + ln) * 8];
            bf16x8 fb11 = *(const bf16x8*)&f_lds[cur][(jf1 * 64 + 32 + ln) * 8];
            S0 = __builtin_amdgcn_mfma_f32_32x32x16_bf16(ga0, fb00, S0, 0, 0, 0);
            S0 = __builtin_amdgcn_mfma_f32_32x32x16_bf16(gl0, fb00, S0, 0, 0, 0);
            S0 = __builtin_amdgcn_mfma_f32_32x32x16_bf16(ga1, fb10, S0, 0, 0, 0);
            S0 = __builtin_amdgcn_mfma_f32_32x32x16_bf16(gl1, fb10, S0, 0, 0, 0);
            S1 = __builtin_amdgcn_mfma_f32_32x32x16_bf16(ga0, fb01, S1, 0, 0, 0);
            S1 = __builtin_amdgcn_mfma_f32_32x32x16_bf16(gl0, fb01, S1, 0, 0, 0);
            S1 = __builtin_amdgcn_mfma_f32_32x32x16_bf16(ga1, fb11, S1, 0, 0, 0);
            S1 = __builtin_amdgcn_mfma_f32_32x32x16_bf16(gl1, fb11, S1, 0, 0, 0);
        }

        // ---- p = exp(s) (no-max softmax, |s|<~40 R2-proven; clamp = insurance)
        {
            const int jw = ln >> 3, pi = ln & 7;
            #pragma unroll
            for (int r = 0; r < 16; ++r) {
                int q = w * 32 + (r & 3) + 8 * (r >> 2) + 4 * hl;
                float p0 = __expf(fminf(S0[r], 80.f));
                float p1 = __expf(fminf(S1[r], 80.f));
                lsum[r] += p0 + p1;
                p_lds[(q * 8 + ((jw + q) & 7)) * 8 + pi]     = f2bf(p0);
                p_lds[(q * 8 + ((jw + 4 + q) & 7)) * 8 + pi] = f2bf(p1);
            }
        }
        __syncthreads();   // MID: P visible (nothing outstanding -> free drain)

        // ---- stage macro kt+1 (drains at TOP(kt+1), covered by PV below)
        if (kt + 1 < NMACRO) {
            const int nxt = cur ^ 1;
            const long long tb = (long long)(kt + 1) * (CDIM * 64);
            #pragma unroll
            for (int i = 0; i < 4; ++i) {
                int s = i * 256 + tid;
                int c = s >> 3, j = ((s & 7) - c) & 7;
                LDS_ASYNC16(htb + tb + (long long)(chs * 128 + c) * 64 + j * 8,
                            &hh_lds[nxt][s * 8]);
            }
            LDS_ASYNC16(fbase + (long long)((kt + 1) * 64 + (tid & 63)) * CKD + (tid >> 6) * 8,
                        &f_lds[nxt][tid * 8]);
        }

        // ---- PV: 2x2 register tiles over K=64
        const int qv = (w & 1) * 64, cv = (w >> 1) * 64;
        #pragma unroll
        for (int ks = 0; ks < 4; ++ks) {
            const int j = ks * 2 + hl;
            const int qa = qv + ln, qb2 = qv + 32 + ln;
            const int ca = cv + ln, cb2 = cv + 32 + ln;
            bf16x8 pa0 = *(const bf16x8*)&p_lds[(qa * 8 + ((j + qa) & 7)) * 8];
            bf16x8 pa1 = *(const bf16x8*)&p_lds[(qb2 * 8 + ((j + qb2) & 7)) * 8];
            bf16x8 hb0 = *(const bf16x8*)&hh_lds[cur][(ca * 8 + ((j + ca) & 7)) * 8];
            bf16x8 hb1 = *(const bf16x8*)&hh_lds[cur][(cb2 * 8 + ((j + cb2) & 7)) * 8];
            acc00 = __builtin_amdgcn_mfma_f32_32x32x16_bf16(pa0, hb0, acc00, 0, 0, 0);
            acc01 = __builtin_amdgcn_mfma_f32_32x32x16_bf16(pa0, hb1, acc01, 0, 0, 0);
            acc10 = __builtin_amdgcn_mfma_f32_32x32x16_bf16(pa1, hb0, acc10, 0, 0, 0);
            acc11 = __builtin_amdgcn_mfma_f32_32x32x16_bf16(pa1, hb1, acc11, 0, 0, 0);
        }
    }

    // ---- l: reduce 32 key-cols (within half), publish per q-band
    #pragma unroll
    for (int m = 1; m <= 16; m <<= 1)
        #pragma unroll
        for (int r = 0; r < 16; ++r)
            lsum[r] += __shfl_xor(lsum[r], m, 64);
    if (ln == 0) {
        #pragma unroll
        for (int r = 0; r < 16; ++r)
            l_red[w * 32 + (r & 3) + 8 * (r >> 2) + 4 * hl] = lsum[r];
    }
    __syncthreads();

    // ---- epilogue: out = x + o/l
    const int qv = (w & 1) * 64, cv = chs * 128 + (w >> 1) * 64;
    #pragma unroll
    for (int r = 0; r < 16; ++r) {
        const int rowD = (r & 3) + 8 * (r >> 2) + 4 * hl;
        {
            int ql = qv + rowD;
            float linv = 1.f / l_red[ql];
            long long rg = (bbase + q0 + ql) * CDIM + cv + ln;
            out[rg]      = x[rg]      + acc00[r] * linv;
            out[rg + 32] = x[rg + 32] + acc01[r] * linv;
        }
        {
            int ql = qv + 32 + rowD;
            float linv = 1.f / l_red[ql];
            long long rg = (bbase + q0 + ql) * CDIM + cv + ln;
            out[rg]      = x[rg]      + acc10[r] * linv;
            out[rg + 32] = x[rg + 32] + acc11[r] * linv;
        }
    }
}

extern "C" void kernel_launch(void* const* d_in, const int* in_sizes, int n_in,
                              void* d_out, int out_size, void* d_ws, size_t ws_size,
                              hipStream_t stream) {
    const float* x  = (const float*)d_in[0];
    const float* Wf = (const float*)d_in[1];
    const float* bf = (const float*)d_in[2];
    const float* Wg = (const float*)d_in[3];
    const float* bg = (const float*)d_in[4];
    const float* Wh = (const float*)d_in[5];
    const float* bh = (const float*)d_in[6];
    float* out = (float*)d_out;

    ushort* fbf = (ushort*)d_ws;                 // bf16 keys      [B*N,32]
    ushort* gbf = fbf + BATCH * NPIX * CKD;      // bf16 queries   [B*N,32]
    ushort* glo = gbf + BATCH * NPIX * CKD;      // bf16 q-residual[B*N,32]
    ushort* ht  = glo + BATCH * NPIX * CKD;      // bf16 tiled values^T
    ushort* Wt  = ht + BATCH * NPIX * CDIM;      // bf16 [320,256]

    prep_kernel<<<dim3(256), 256, 0, stream>>>(Wh, Wf, Wg, Wt);
    proj_kernel<<<dim3(256), 256, 0, stream>>>(x, Wt, bf, bg, bh, fbf, gbf, glo, ht);
    attn_kernel<<<dim3(256), 256, 0, stream>>>(x, fbf, gbf, glo, ht, out);
}

// Round 7
// 173.460 us; speedup vs baseline: 1.6495x; 1.2270x over previous
//
#include <hip/hip_runtime.h>
#include <math.h>

#define CDIM 256
#define CKD  32
#define NPIX 4096
#define BATCH 4
#define NMACRO (NPIX / 64)

typedef __attribute__((ext_vector_type(8)))  short bf16x8;
typedef __attribute__((ext_vector_type(16))) float f32x16;

__device__ inline ushort f2bf(float x) {
    unsigned u = __float_as_uint(x);
    u += 0x7fffu + ((u >> 16) & 1u);   // round-to-nearest-even
    return (ushort)(u >> 16);
}
__device__ inline unsigned packbf(float a, float b) {
    return (unsigned)f2bf(a) | ((unsigned)f2bf(b) << 16);
}

#define LDS_ASYNC16(gptr, lptr) \
  __builtin_amdgcn_global_load_lds((const __attribute__((address_space(1))) void*)(gptr), \
                                   (__attribute__((address_space(3))) void*)(lptr), 16, 0, 0)

// ---------------- Kernel 0: prep Wt[320][256] bf16 = [Wh^T; Wf^T; Wg^T] ----
__global__ __launch_bounds__(256) void prep_kernel(
    const float* __restrict__ Wh, const float* __restrict__ Wf,
    const float* __restrict__ Wg, ushort* __restrict__ Wt)
{
    const int k = blockIdx.x;
    const int c = threadIdx.x;
    Wt[c * 256 + k] = f2bf(Wh[k * 256 + c]);
    if (c < 32)
        Wt[(256 + c) * 256 + k] = f2bf(Wf[k * CKD + c]);
    else if (c < 64)
        Wt[(288 + (c - 32)) * 256 + k] = f2bf(Wg[k * CKD + (c - 32)]);
}

// ---------------- Kernel 1: MFMA projections ------------------------------
// 512 blocks (2/CU -> 2 waves/SIMD), 4 waves, 32 px each. K=256, 8 slabs.
// Wave w: hh c-rows w*64..w*64+63 (2 C-tiles, D[row=c][col=px] -> tiled ht).
// Waves 0/1 additionally compute f/g (D[row=px][col=out]).
// wls chunk (n,o) at slot n*4 + ((o + (n>>1))&3)  [R6-verified layout]
// xls chunk (px,o) at slot o*32 + px
__global__ __launch_bounds__(256) void proj_kernel(
    const float*  __restrict__ x,    // [B*N, 256] fp32
    const ushort* __restrict__ Wt,   // [320, 256] bf16
    const float*  __restrict__ bfp, const float* __restrict__ bgp,
    const float*  __restrict__ bhp,
    ushort* __restrict__ fo,         // bf16 [B*N, 32]
    ushort* __restrict__ go,         // bf16 [B*N, 32]
    ushort* __restrict__ glo,        // bf16 [B*N, 32]  g residual
    ushort* __restrict__ ht)         // bf16 [B*64][256][64] tiled values^T
{
    __shared__ ushort wls[2][1280 * 8];   // 20 KB each
    __shared__ ushort xls[2][128 * 8];    //  2 KB each

    const int tid  = threadIdx.x;
    const int w    = tid >> 6;
    const int lane = tid & 63;
    const int hl   = lane >> 5;
    const int ln   = lane & 31;
    const int bid  = blockIdx.x;
    const long long px0 = (long long)bid * 32;
    const int b    = (int)(px0 >> 12);
    const int n0   = (int)(px0 & (NPIX - 1));
    const int kt   = n0 >> 6;          // 64-key tile index
    const int koff = n0 & 63;          // 0 or 32

    // x staging map: thread -> (px = tid&31, quad jq = tid>>5 of 4 ck)
    const int sx_px = tid & 31, sx_jq = tid >> 5;

    // ---- stage slab 0
    #pragma unroll
    for (int i = 0; i < 5; ++i) {
        int s = i * 256 + tid;
        int n = s >> 2, o = ((s & 3) - (n >> 1)) & 3;
        LDS_ASYNC16(Wt + n * 256 + o * 8, &wls[0][s * 8]);
    }
    {
        float4 v = *(const float4*)(x + (px0 + sx_px) * CDIM + sx_jq * 4);
        uint2 p; p.x = packbf(v.x, v.y); p.y = packbf(v.z, v.w);
        *(uint2*)&xls[0][((sx_jq >> 1) * 32 + sx_px) * 8 + (sx_jq & 1) * 4] = p;
    }

    f32x16 acc0={0,0,0,0,0,0,0,0,0,0,0,0,0,0,0,0};
    f32x16 acc1={0,0,0,0,0,0,0,0,0,0,0,0,0,0,0,0};
    f32x16 accfg={0,0,0,0,0,0,0,0,0,0,0,0,0,0,0,0};

    for (int sl = 0; sl < 8; ++sl) {
        const int cur = sl & 1;
        __syncthreads();
        if (sl + 1 < 8) {
            const int nxt = cur ^ 1;
            #pragma unroll
            for (int i = 0; i < 5; ++i) {
                int s = i * 256 + tid;
                int n = s >> 2, o = ((s & 3) - (n >> 1)) & 3;
                LDS_ASYNC16(Wt + n * 256 + (sl + 1) * 32 + o * 8, &wls[nxt][s * 8]);
            }
            float4 v = *(const float4*)(x + (px0 + sx_px) * CDIM + (sl + 1) * 32 + sx_jq * 4);
            uint2 p; p.x = packbf(v.x, v.y); p.y = packbf(v.z, v.w);
            *(uint2*)&xls[nxt][((sx_jq >> 1) * 32 + sx_px) * 8 + (sx_jq & 1) * 4] = p;
        }

        #pragma unroll
        for (int st = 0; st < 2; ++st) {
            const int o = st * 2 + hl;
            #define LDW(n) (*(const bf16x8*)&wls[cur][((n) * 4 + (((o) + ((n) >> 1)) & 3)) * 8])
            bf16x8 xb  = *(const bf16x8*)&xls[cur][(o * 32 + ln) * 8];
            bf16x8 wa0 = LDW(w * 64 + ln);
            bf16x8 wa1 = LDW(w * 64 + 32 + ln);
            acc0 = __builtin_amdgcn_mfma_f32_32x32x16_bf16(wa0, xb, acc0, 0, 0, 0);
            acc1 = __builtin_amdgcn_mfma_f32_32x32x16_bf16(wa1, xb, acc1, 0, 0, 0);
            if (w < 2) {
                bf16x8 wfg = LDW(256 + w * 32 + ln);
                accfg = __builtin_amdgcn_mfma_f32_32x32x16_bf16(xb, wfg, accfg, 0, 0, 0);
            }
            #undef LDW
        }
    }

    // ---- epilogue: hh -> tiled ht (D row = channel, D col = pixel)
    ushort* htt = ht + ((long long)(b * 64 + kt) * CDIM) * 64 + koff;
    #pragma unroll
    for (int r = 0; r < 16; ++r) {
        const int rowD = (r & 3) + 8 * (r >> 2) + 4 * hl;
        int c0 = w * 64 + rowD, c1 = c0 + 32;
        htt[(long long)c0 * 64 + ln] = f2bf(acc0[r] + bhp[c0]);
        htt[(long long)c1 * 64 + ln] = f2bf(acc1[r] + bhp[c1]);
    }
    // ---- f/g epilogue (waves 0/1): D row = pixel, D col = out
    if (w < 2) {
        const float bb = (w ? bgp : bfp)[ln];
        #pragma unroll
        for (int r = 0; r < 16; ++r) {
            const int rowD = (r & 3) + 8 * (r >> 2) + 4 * hl;
            float v = accfg[r] + bb;
            ushort hi = f2bf(v);
            long long idx = (px0 + rowD) * CKD + ln;
            if (w == 0) {
                fo[idx] = hi;
            } else {
                go[idx] = hi;
                float hif = __uint_as_float(((unsigned)hi) << 16);
                glo[idx] = f2bf(v - hif);
            }
        }
    }
}

// ---------------- Kernel 2: MFMA attention --------------------------------
// 512 blocks (2/CU -> 2 waves/SIMD), 4 waves. Block = 64 q x 128 ch
// (ch-split 2), 64-key macros, dbuf hh+f.
// Wave w = (qb=w&1, kh=w>>1): QK computes S^T(32k x 32q) = MFMA(A=f, B=g)
// so exp values sit col=q=lane -> packed b64 P-writes (A-layout chunks).
// PV: wave w -> O(q-band qb x c-half kh), K=64, 8 MFMAs / 12 reads.
// Chunk layouts (16 B): hh slot(c,j)=c*8+((j+c)&7); p slot(q,j)=q*8+((j+q)&7);
// f slot(key,j)=j*64+key.
__global__ __launch_bounds__(256) void attn_kernel(
    const float*  __restrict__ x,
    const ushort* __restrict__ fk,   // bf16 [B*N,32] keys
    const ushort* __restrict__ gq,   // bf16 [B*N,32] queries (hi)
    const ushort* __restrict__ glo,  // bf16 [B*N,32] queries (lo residual)
    const ushort* __restrict__ hv,   // bf16 tiled [B*64][256][64] values^T
    float* __restrict__ out)
{
    __shared__ ushort hh_lds[2][1024 * 8];  // 16 KB each
    __shared__ ushort f_lds[2][256 * 8];    //  4 KB each
    __shared__ ushort p_lds[512 * 8];       //  8 KB
    __shared__ float  l_red[2][64];

    const int tid  = threadIdx.x;
    const int w    = tid >> 6;
    const int lane = tid & 63;
    const int hl   = lane >> 5;
    const int ln   = lane & 31;

    const int bid = blockIdx.x;
    const int chs = bid & 1;
    const int b   = (bid >> 1) & 3;
    const int qt  = bid >> 3;            // 0..63
    const int q0  = qt * 64;

    const int qb = w & 1;                // q-band (QK and PV)
    const int kh = w >> 1;               // key-half (QK) / c-half (PV)

    const long long bbase = (long long)b * NPIX;
    const ushort* fbase = fk + bbase * CKD;
    const ushort* htb   = hv + (long long)b * 64 * (CDIM * 64);

    // g B-frags (hi+lo), registers all kernel
    const ushort* gp  = gq  + (bbase + q0 + qb * 32 + ln) * CKD;
    const ushort* glp = glo + (bbase + q0 + qb * 32 + ln) * CKD;
    const bf16x8 ga0 = *(const bf16x8*)(gp + hl * 8);
    const bf16x8 ga1 = *(const bf16x8*)(gp + 16 + hl * 8);
    const bf16x8 gl0 = *(const bf16x8*)(glp + hl * 8);
    const bf16x8 gl1 = *(const bf16x8*)(glp + 16 + hl * 8);

    // ---- stage macro 0 (dests lane-linear: s = i*256+tid)
    #pragma unroll
    for (int i = 0; i < 4; ++i) {
        int s = i * 256 + tid;
        int c = s >> 3, j = ((s & 7) - c) & 7;
        LDS_ASYNC16(htb + (long long)(chs * 128 + c) * 64 + j * 8, &hh_lds[0][s * 8]);
    }
    LDS_ASYNC16(fbase + (long long)(tid & 63) * CKD + (tid >> 6) * 8, &f_lds[0][tid * 8]);

    f32x16 accA={0,0,0,0,0,0,0,0,0,0,0,0,0,0,0,0};   // c-subtile 0
    f32x16 accB={0,0,0,0,0,0,0,0,0,0,0,0,0,0,0,0};   // c-subtile 1
    float lsum = 0.f;

    for (int kt = 0; kt < NMACRO; ++kt) {
        const int cur = kt & 1;
        __syncthreads();   // TOP: staging(kt) drained; prior PV p-reads retired

        // ---- QK: S^T(32k x 32q) = f(A) . g(B), hi+lo
        f32x16 S={0,0,0,0,0,0,0,0,0,0,0,0,0,0,0,0};
        {
            bf16x8 fb0 = *(const bf16x8*)&f_lds[cur][((hl)     * 64 + kh * 32 + ln) * 8];
            bf16x8 fb1 = *(const bf16x8*)&f_lds[cur][((2 + hl) * 64 + kh * 32 + ln) * 8];
            S = __builtin_amdgcn_mfma_f32_32x32x16_bf16(fb0, ga0, S, 0, 0, 0);
            S = __builtin_amdgcn_mfma_f32_32x32x16_bf16(fb0, gl0, S, 0, 0, 0);
            S = __builtin_amdgcn_mfma_f32_32x32x16_bf16(fb1, ga1, S, 0, 0, 0);
            S = __builtin_amdgcn_mfma_f32_32x32x16_bf16(fb1, gl1, S, 0, 0, 0);
        }

        // ---- p = exp(s) (no-max softmax; clamp = insurance), packed b64 writes
        {
            float p[16];
            #pragma unroll
            for (int r = 0; r < 16; ++r) {
                p[r] = __expf(fminf(S[r], 80.f));
                lsum += p[r];
            }
            const int q = qb * 32 + ln;
            #pragma unroll
            for (int m = 0; m < 4; ++m) {
                // pair (d0,d1) covers keys {8m..8m+3}+4hl of this kh-half
                uint2 d;
                d.x = packbf(p[4 * m + 0], p[4 * m + 1]);
                d.y = packbf(p[4 * m + 2], p[4 * m + 3]);
                int oct = kh * 4 + m;
                int slot = q * 8 + ((oct + q) & 7);
                *(uint2*)&p_lds[slot * 8 + hl * 4] = d;
            }
        }
        __syncthreads();   // MID: P visible (nothing outstanding -> free drain)

        // ---- stage macro kt+1 (drains at TOP(kt+1), covered by PV)
        if (kt + 1 < NMACRO) {
            const int nxt = cur ^ 1;
            const long long tb = (long long)(kt + 1) * (CDIM * 64);
            #pragma unroll
            for (int i = 0; i < 4; ++i) {
                int s = i * 256 + tid;
                int c = s >> 3, j = ((s & 7) - c) & 7;
                LDS_ASYNC16(htb + tb + (long long)(chs * 128 + c) * 64 + j * 8,
                            &hh_lds[nxt][s * 8]);
            }
            LDS_ASYNC16(fbase + (long long)((kt + 1) * 64 + (tid & 63)) * CKD + (tid >> 6) * 8,
                        &f_lds[nxt][tid * 8]);
        }

        // ---- PV: O(32q x 64c) over K=64 (4 chunks of 16)
        const int qa = qb * 32 + ln;
        const int ca = kh * 64 + ln, cb2 = kh * 64 + 32 + ln;
        #pragma unroll
        for (int ch = 0; ch < 4; ++ch) {
            const int oct = ch * 2 + hl;
            bf16x8 pa = *(const bf16x8*)&p_lds[(qa * 8 + ((oct + qa) & 7)) * 8];
            bf16x8 h0 = *(const bf16x8*)&hh_lds[cur][(ca  * 8 + ((oct + ca)  & 7)) * 8];
            bf16x8 h1 = *(const bf16x8*)&hh_lds[cur][(cb2 * 8 + ((oct + cb2) & 7)) * 8];
            accA = __builtin_amdgcn_mfma_f32_32x32x16_bf16(pa, h0, accA, 0, 0, 0);
            accB = __builtin_amdgcn_mfma_f32_32x32x16_bf16(pa, h1, accB, 0, 0, 0);
        }
    }

    // ---- l: both halves hold disjoint key-rows for q=ln -> swap-add,
    //      then combine the two kh waves via LDS
    lsum += __shfl_xor(lsum, 32);
    if (hl == 0) l_red[kh][qb * 32 + ln] = lsum;
    __syncthreads();

    // ---- epilogue: out = x + o/l
    #pragma unroll
    for (int r = 0; r < 16; ++r) {
        const int rowD = (r & 3) + 8 * (r >> 2) + 4 * hl;
        const int ql = qb * 32 + rowD;
        float linv = 1.f / (l_red[0][ql] + l_red[1][ql]);
        long long rg = (bbase + q0 + ql) * CDIM + chs * 128 + kh * 64 + ln;
        out[rg]      = x[rg]      + accA[r] * linv;
        out[rg + 32] = x[rg + 32] + accB[r] * linv;
    }
}

extern "C" void kernel_launch(void* const* d_in, const int* in_sizes, int n_in,
                              void* d_out, int out_size, void* d_ws, size_t ws_size,
                              hipStream_t stream) {
    const float* x  = (const float*)d_in[0];
    const float* Wf = (const float*)d_in[1];
    const float* bf = (const float*)d_in[2];
    const float* Wg = (const float*)d_in[3];
    const float* bg = (const float*)d_in[4];
    const float* Wh = (const float*)d_in[5];
    const float* bh = (const float*)d_in[6];
    float* out = (float*)d_out;

    ushort* fbf = (ushort*)d_ws;                 // bf16 keys      [B*N,32]
    ushort* gbf = fbf + BATCH * NPIX * CKD;      // bf16 queries   [B*N,32]
    ushort* glo = gbf + BATCH * NPIX * CKD;      // bf16 q-residual[B*N,32]
    ushort* ht  = glo + BATCH * NPIX * CKD;      // bf16 tiled values^T
    ushort* Wt  = ht + BATCH * NPIX * CDIM;      // bf16 [320,256]

    prep_kernel<<<dim3(256), 256, 0, stream>>>(Wh, Wf, Wg, Wt);
    proj_kernel<<<dim3(512), 256, 0, stream>>>(x, Wt, bf, bg, bh, fbf, gbf, glo, ht);
    attn_kernel<<<dim3(512), 256, 0, stream>>>(x, fbf, gbf, glo, ht, out);
}